// Round 3
// baseline (590.311 us; speedup 1.0000x reference)
//
#include <hip/hip_runtime.h>
#include <math.h>

// LocalAggregationLoss — R2: concurrency restructure.
//   prep:   v = normalize(codes) -> ws ; zero accumulators
//   gather: 1024 x 5 blocks, 256 thr, launch_bounds(256,8) targeting <=64 VGPR
//           -> 32 waves/CU (2x R1). Each 32-lane group: 5 bg + 5 cl rows.
//           Block partials combined with 2 atomicAdds into ws accumulators.
//   finish: out[b] = log(d1) - log(d2)
// Gather traffic ~210 MB of random 512B rows from 512MB bank; floor ~30-35 us.

constexpr int DIM    = 128;
constexpr int KN     = 200;
constexpr int CHUNKS = 5;
constexpr int RPC    = KN / CHUNKS;   // 40 rows per chunk per array
constexpr int RPG    = RPC / 8;       // 5 rows per 32-lane group per array
constexpr float INV_T = 1.0f / 0.07f;

// ---- prep: normalize codes[b] into ws_v, zero the two accumulators ----
__global__ __launch_bounds__(64)
void prep_kernel(const float* __restrict__ codes,
                 float* __restrict__ ws_v,
                 float* __restrict__ acc)
{
    const int b = blockIdx.x;
    const int t = threadIdx.x;
    float2 c2 = ((const float2*)(codes + (size_t)b * DIM))[t];
    float ss = c2.x * c2.x + c2.y * c2.y;
    #pragma unroll
    for (int m = 32; m > 0; m >>= 1) ss += __shfl_xor(ss, m, 64);
    const float rn = 1.0f / sqrtf(ss);
    float2 o; o.x = c2.x * rn; o.y = c2.y * rn;
    ((float2*)(ws_v + (size_t)b * DIM))[t] = o;
    if (t < 2) acc[b * 2 + t] = 0.0f;
}

// ---- gather: one block = (batch b, chunk of 40 rows per array) ----
__global__ __launch_bounds__(256, 8)
void gather_kernel(const float* __restrict__ bank,
                   const float* __restrict__ ws_v,
                   const int*   __restrict__ idx_bg,
                   const int*   __restrict__ idx_cl,
                   float*       __restrict__ acc)
{
    const int b     = blockIdx.x;
    const int chunk = blockIdx.y;
    const int tid   = threadIdx.x;
    const int g     = tid >> 5;   // 0..7
    const int lane  = tid & 31;   // 0..31

    const float4 vv = ((const float4*)(ws_v + (size_t)b * DIM))[lane];

    const int kb = chunk * RPC + g * RPG;
    const int* ib = idx_bg + b * KN + kb;
    const int* ic = idx_cl + b * KN + kb;

    // all 10 indices up front (off the critical path)
    int r1[RPG], r2[RPG];
    #pragma unroll
    for (int u = 0; u < RPG; ++u) { r1[u] = ib[u]; r2[u] = ic[u]; }

    float sum1 = 0.0f, sum2 = 0.0f;
    float4 x[RPG];

    // bg rows: issue 5 coalesced 512B loads
    #pragma unroll
    for (int u = 0; u < RPG; ++u)
        x[u] = ((const float4*)(bank + (size_t)r1[u] * DIM))[lane];

    // consume bg, refill slot with cl row (keeps ~5 loads in flight)
    #pragma unroll
    for (int u = 0; u < RPG; ++u) {
        const float4 xu = x[u];
        x[u] = ((const float4*)(bank + (size_t)r2[u] * DIM))[lane];
        float d = xu.x * vv.x + xu.y * vv.y + xu.z * vv.z + xu.w * vv.w;
        #pragma unroll
        for (int m = 16; m > 0; m >>= 1) d += __shfl_xor(d, m, 64);
        sum1 += __expf(d * INV_T);
    }
    // consume cl
    #pragma unroll
    for (int u = 0; u < RPG; ++u) {
        float d = x[u].x * vv.x + x[u].y * vv.y + x[u].z * vv.z + x[u].w * vv.w;
        #pragma unroll
        for (int m = 16; m > 0; m >>= 1) d += __shfl_xor(d, m, 64);
        sum2 += __expf(d * INV_T);
    }

    __shared__ float red1[8], red2[8];
    if (lane == 0) { red1[g] = sum1; red2[g] = sum2; }
    __syncthreads();
    if (tid == 0) {
        float D1 = 0.0f, D2 = 0.0f;
        #pragma unroll
        for (int i = 0; i < 8; ++i) { D1 += red1[i]; D2 += red2[i]; }
        atomicAdd(&acc[b * 2 + 0], D1);
        atomicAdd(&acc[b * 2 + 1], D2);
    }
}

// ---- finish: log-diff ----
__global__ void finish_kernel(const float* __restrict__ acc,
                              float* __restrict__ out, int batch)
{
    const int i = blockIdx.x * blockDim.x + threadIdx.x;
    if (i < batch) out[i] = logf(acc[2 * i]) - logf(acc[2 * i + 1]);
}

extern "C" void kernel_launch(void* const* d_in, const int* in_sizes, int n_in,
                              void* d_out, int out_size, void* d_ws, size_t ws_size,
                              hipStream_t stream)
{
    const float* codes  = (const float*)d_in[0];
    const float* bank   = (const float*)d_in[1];
    const int*   idx_bg = (const int*)d_in[2];
    const int*   idx_cl = (const int*)d_in[3];
    float*       out    = (float*)d_out;

    const int batch = in_sizes[0] / DIM;   // 1024

    float* ws_v = (float*)d_ws;                       // batch*DIM floats
    float* acc  = ws_v + (size_t)batch * DIM;         // 2*batch floats

    prep_kernel<<<batch, 64, 0, stream>>>(codes, ws_v, acc);
    gather_kernel<<<dim3(batch, CHUNKS), 256, 0, stream>>>(bank, ws_v, idx_bg, idx_cl, acc);
    finish_kernel<<<(batch + 255) / 256, 256, 0, stream>>>(acc, out, batch);
}